// Round 2
// baseline (359.603 us; speedup 1.0000x reference)
//
#include <hip/hip_runtime.h>

#define BB 8
#define PP 16384
#define MM 16
#define CIc 16
#define COc 32
#define WW 17

// One block per point p. 256 threads. All data fp32.
// Phase 0: cooperative loads (ww, wres, self rows, gathered neighbors) -> LDS
// Phase 1: A[b][w][i] = sum_m ww[m][w] * X[b][m][i]   (8*272 outputs)
// Phase 2: thread (b,o): conv = sum_{w,i} A[b][w][i]*weights[w][o*16+i]; elu; + residual
__global__ __launch_bounds__(256, 2) void pconv_kernel(
    const float* __restrict__ in_pc,       // (B,P,CI) f32
    const float* __restrict__ weights,     // (W, CO*CI) f32
    const float* __restrict__ bias,        // (P, CO) f32
    const float* __restrict__ w_weights,   // (P, M, W) f32
    const float* __restrict__ weight_res,  // (CO, CI) f32
    const int* __restrict__ neighbor_id,   // (P, M) int32
    float* __restrict__ out)               // (B,P,CO) f32
{
  __shared__ __attribute__((aligned(16))) float Xs[BB * MM * CIc];   // 2048 f
  __shared__ __attribute__((aligned(16))) float As[BB * WW * CIc];   // 2176 f
  __shared__ __attribute__((aligned(16))) float wws[MM * WW];        // 272 f
  __shared__ __attribute__((aligned(16))) float wrs[COc * CIc];      // 512 f
  __shared__ __attribute__((aligned(16))) float selfs[BB * CIc];     // 128 f

  const int p = blockIdx.x;
  const int tid = threadIdx.x;

  // --- ww[p]: 272 f32; threads 0..67 load float4 (p*272*4 bytes = p*1088, 16B-aligned) ---
  if (tid < 68) {
    float4 v = *(const float4*)(w_weights + (size_t)p * (MM * WW) + tid * 4);
    *(float4*)(wws + tid * 4) = v;
  }
  // --- weight_res: 512 f32; threads 128..255 load float4 ---
  if (tid >= 128) {
    int t = tid - 128;
    *(float4*)(wrs + t * 4) = *(const float4*)(weight_res + t * 4);
  }
  // --- self rows in_pc[b,p,:]: threads 68..99 (32 threads, float4 each) ---
  if (tid >= 68 && tid < 100) {
    int t2 = tid - 68;
    int b = t2 >> 2, q = t2 & 3;
    *(float4*)(selfs + b * CIc + q * 4) =
        *(const float4*)(in_pc + ((size_t)b * PP + p) * CIc + q * 4);
  }
  // --- gather X[b][m][:]: all 256 threads, each loads 8 f32 (two float4) ---
  {
    int b = tid >> 5, m = (tid >> 1) & 15, half = tid & 1;
    int nid = neighbor_id[p * MM + m];
    float4 v0, v1;
    if (nid == PP) {
      v0 = make_float4(0.f, 0.f, 0.f, 0.f);
      v1 = v0;
    } else {
      const float* src = in_pc + ((size_t)b * PP + nid) * CIc + half * 8;
      v0 = *(const float4*)(src);
      v1 = *(const float4*)(src + 4);
    }
    float* dst = Xs + (b * MM + m) * CIc + half * 8;
    *(float4*)(dst) = v0;
    *(float4*)(dst + 4) = v1;
  }
  __syncthreads();

  // --- Phase 1: A[b][wi], wi in [0,272); thread j of each 32-thread b-group owns
  //     wi = j, j+32, ... (i = wi&15 = j&15 invariant -> cache X column in regs) ---
  {
    int b = tid >> 5, j = tid & 31, i = j & 15;
    float x[MM];
#pragma unroll
    for (int m = 0; m < MM; m++) x[m] = Xs[(b * MM + m) * CIc + i];
#pragma unroll
    for (int k = 0; k < 9; k++) {
      int wi = j + 32 * k;
      if (wi < WW * CIc) {
        int w = wi >> 4;
        float acc = 0.f;
#pragma unroll
        for (int m = 0; m < MM; m++) acc += wws[m * WW + w] * x[m];
        As[b * (WW * CIc) + wi] = acc;
      }
    }
  }
  __syncthreads();

  // --- Phase 2: thread (b,o) ---
  {
    int b = tid >> 5, o = tid & 31;
    float conv = 0.f;
#pragma unroll
    for (int w = 0; w < WW; w++) {
      const float4* Ap = (const float4*)&As[b * (WW * CIc) + w * CIc];
      float4 a0 = Ap[0], a1 = Ap[1], a2 = Ap[2], a3 = Ap[3];
      const float4* wp = (const float4*)(weights + w * (COc * CIc) + o * CIc);
      float4 w0 = wp[0], w1 = wp[1], w2 = wp[2], w3 = wp[3];
      conv += a0.x * w0.x + a0.y * w0.y + a0.z * w0.z + a0.w * w0.w;
      conv += a1.x * w1.x + a1.y * w1.y + a1.z * w1.z + a1.w * w1.w;
      conv += a2.x * w2.x + a2.y * w2.y + a2.z * w2.z + a2.w * w2.w;
      conv += a3.x * w3.x + a3.y * w3.y + a3.z * w3.z + a3.w * w3.w;
    }
    conv += bias[p * COc + o];

    float res = 0.f;
#pragma unroll
    for (int i = 0; i < CIc; i += 4) {
      res += wrs[o * CIc + i + 0] * selfs[b * CIc + i + 0];
      res += wrs[o * CIc + i + 1] * selfs[b * CIc + i + 1];
      res += wrs[o * CIc + i + 2] * selfs[b * CIc + i + 2];
      res += wrs[o * CIc + i + 3] * selfs[b * CIc + i + 3];
    }

    float e = conv > 0.f ? conv : (__expf(conv) - 1.f);
    const float SQ = 0.70710678118654752440f;  // sqrt(0.5), both branches
    out[((size_t)b * PP + p) * COc + o] = SQ * e + SQ * res;
  }
}

extern "C" void kernel_launch(void* const* d_in, const int* in_sizes, int n_in,
                              void* d_out, int out_size, void* d_ws, size_t ws_size,
                              hipStream_t stream) {
  const float* in_pc       = (const float*)d_in[0];
  const float* weights     = (const float*)d_in[1];
  const float* bias        = (const float*)d_in[2];
  const float* w_weights   = (const float*)d_in[3];
  const float* weight_res  = (const float*)d_in[4];
  const int*   neighbor_id = (const int*)d_in[5];
  float* out = (float*)d_out;

  hipLaunchKernelGGL(pconv_kernel, dim3(PP), dim3(256), 0, stream,
                     in_pc, weights, bias, w_weights, weight_res, neighbor_id, out);
}

// Round 3
// 131.693 us; speedup vs baseline: 2.7306x; 2.7306x over previous
//
#include <hip/hip_runtime.h>

#define PP 16384
#define SQH 0.70710678118654752440f  // sqrt(0.5), both conv and res factors

typedef unsigned int u32;
typedef unsigned short u16;
typedef __attribute__((ext_vector_type(8))) short bfrag;   // 8 bf16 (4 VGPRs)
typedef __attribute__((ext_vector_type(4))) float ffrag;   // MFMA C/D
typedef __attribute__((ext_vector_type(4))) float f4;
typedef __attribute__((ext_vector_type(2))) float f2;

union BU { bfrag v; uint4 u; };

// pack two f32 -> one dword of two bf16 (round-half-away; values are small/finite)
__device__ __forceinline__ u32 pk2(float a, float b) {
  u32 ua = __float_as_uint(a), ub = __float_as_uint(b);
  return ((ua + 0x8000u) >> 16) | ((ub + 0x8000u) & 0xffff0000u);
}

// Block = 256 thr = 4 waves. Each wave independently processes 4 point-pairs
// (8 points). One barrier total (weight staging). Per pair:
//   phase1 (VALU): A[r=pt*8+b][k=w*16+i] = sum_m ww[p,m,w]*X[b,m,i], ww via s_loads,
//                  X gathered global->reg; A packed bf16 -> per-wave LDS (row stride 296).
//   phase2 (MFMA): C[16x32] = A[16x288] * W[288x32], 9 K-steps x 2 N-tiles,
//                  + 1 residual MFMA per N-tile; epilogue: bias, ELU, sqrt(.5) mix.
__global__ __launch_bounds__(256, 2) void pconv_mfma(
    const float* __restrict__ in_pc,       // (8,P,16) f32
    const float* __restrict__ weights,     // (17, 32*16) f32
    const float* __restrict__ bias,        // (P, 32) f32
    const float* __restrict__ w_weights,   // (P, 16, 17) f32
    const float* __restrict__ weight_res,  // (32, 16) f32
    const int*  __restrict__ neighbor_id,  // (P, 16) i32
    float* __restrict__ out)               // (8,P,32) f32
{
  __shared__ __attribute__((aligned(16))) u32 WBs[2 * 9 * 64 * 4];  // 18432 B, B-frag order
  __shared__ __attribute__((aligned(16))) u32 WRs[2 * 64 * 4];      // 2048 B, wres B-frags
  __shared__ __attribute__((aligned(16))) u16 Abuf[4 * 16 * 296];   // 37888 B, per-wave A

  const int tid = threadIdx.x;

  // ---- stage conv weights as bf16 in MFMA B-fragment order, once per block ----
  // entry (nt, ks, l): lane l holds B[k = ks*32 + (l>>4)*8 + j][n = nt*16 + (l&15)]
  for (int e = tid; e < 2 * 9 * 64; e += 256) {
    int nt = e / 576;
    int rem = e - nt * 576;
    int ks = rem >> 6, l = rem & 63;
    int quad = l >> 4, n = l & 15;
    int k0 = ks * 32 + quad * 8;
    uint4 pkd = make_uint4(0u, 0u, 0u, 0u);
    if (k0 < 272) {  // k = w*16+i; 8 consecutive k stay within one w row
      int w = k0 >> 4, i0 = k0 & 15;
      const float* src = weights + w * 512 + (nt * 16 + n) * 16 + i0;
      f4 lo = *(const f4*)src;
      f4 hi = *(const f4*)(src + 4);
      pkd = make_uint4(pk2(lo.x, lo.y), pk2(lo.z, lo.w), pk2(hi.x, hi.y), pk2(hi.z, hi.w));
    }
    *(uint4*)&WBs[e * 4] = pkd;
  }
  // wres B-frags: K=32 step, k=i for k<16 else 0
  for (int e = tid; e < 2 * 64; e += 256) {
    int nt = e >> 6, l = e & 63;
    int quad = l >> 4, n = l & 15;
    uint4 pkd = make_uint4(0u, 0u, 0u, 0u);
    if (quad < 2) {
      const float* src = weight_res + (nt * 16 + n) * 16 + quad * 8;
      f4 lo = *(const f4*)src;
      f4 hi = *(const f4*)(src + 4);
      pkd = make_uint4(pk2(lo.x, lo.y), pk2(lo.z, lo.w), pk2(hi.x, hi.y), pk2(hi.z, hi.w));
    }
    *(uint4*)&WRs[e * 4] = pkd;
  }
  __syncthreads();  // the only barrier

  // readfirstlane => compiler's uniformity analysis sees wid (and everything
  // derived: p, ww base, nid base) as wave-uniform => s_loads for ww/nid.
  const int wid = __builtin_amdgcn_readfirstlane(tid >> 6);
  const int lane = tid & 63;
  const int b_g = lane >> 3, g = lane & 7;       // phase-1 role: (b, i-pair 2g..2g+1)
  const int lo16 = lane & 15, quad = lane >> 4;  // MFMA role
  u16* __restrict__ Aw = Abuf + wid * (16 * 296);

  for (int it = 0; it < 4; ++it) {
    const int pair = (blockIdx.x * 4 + wid) * 4 + it;
    const int p0 = pair * 2;

    // ---------------- phase 1 (both points of the pair) ----------------
#pragma unroll
    for (int pt = 0; pt < 2; ++pt) {
      const int p = p0 + pt;
      const int* __restrict__ nidp = neighbor_id + p * 16;
      const float* __restrict__ wwp = w_weights + (size_t)p * (16 * 17);
      float a0[17], a1[17];
#pragma unroll
      for (int w = 0; w < 17; ++w) { a0[w] = 0.f; a1[w] = 0.f; }
#pragma unroll
      for (int m = 0; m < 16; ++m) {
        int nm = nidp[m];                       // s_load (uniform)
        int nmc = (nm == PP) ? 0 : nm;          // clamp: stay in-bounds
        float msk = (nm == PP) ? 0.f : 1.f;     // pad row contributes zero
        f2 xv = *(const f2*)(in_pc + ((size_t)b_g * PP + nmc) * 16 + 2 * g);
        float x0 = xv.x * msk, x1 = xv.y * msk;
#pragma unroll
        for (int w = 0; w < 17; ++w) {
          float wv = wwp[m * 17 + w];           // s_load (uniform) -> SGPR fmac operand
          a0[w] += wv * x0;
          a1[w] += wv * x1;
        }
      }
      // write A row r = pt*8+b as bf16; k = w*16 + {2g,2g+1}; zero tail k in [272,288)
      u16* arow = Aw + (pt * 8 + b_g) * 296;
#pragma unroll
      for (int w = 0; w < 17; ++w)
        *(u32*)(arow + w * 16 + 2 * g) = pk2(a0[w], a1[w]);
      *(u32*)(arow + 272 + 2 * g) = 0u;
    }

    // ---------------- phase 2: MFMA ----------------
    ffrag acc0 = {0.f, 0.f, 0.f, 0.f}, acc1 = {0.f, 0.f, 0.f, 0.f};
#pragma unroll
    for (int ks = 0; ks < 9; ++ks) {
      bfrag af = *(const bfrag*)(Aw + lo16 * 296 + ks * 32 + quad * 8);
      bfrag bf0 = *(const bfrag*)&WBs[(0 * 576 + ks * 64 + lane) * 4];
      bfrag bf1 = *(const bfrag*)&WBs[(1 * 576 + ks * 64 + lane) * 4];
      acc0 = __builtin_amdgcn_mfma_f32_16x16x32_bf16(af, bf0, acc0, 0, 0, 0);
      acc1 = __builtin_amdgcn_mfma_f32_16x16x32_bf16(af, bf1, acc1, 0, 0, 0);
    }
    // residual: R[16x32] = self[16x16] * wresT, one MFMA per N-tile (K=32, top half zero)
    const int pt_r = lo16 >> 3, b_r = lo16 & 7;
    const int p_r = p0 + pt_r;
    BU su; su.u = make_uint4(0u, 0u, 0u, 0u);
    if (quad < 2) {
      const float* sp = in_pc + ((size_t)b_r * PP + p_r) * 16 + quad * 8;
      f4 lo = *(const f4*)sp;
      f4 hi = *(const f4*)(sp + 4);
      su.u = make_uint4(pk2(lo.x, lo.y), pk2(lo.z, lo.w), pk2(hi.x, hi.y), pk2(hi.z, hi.w));
    }
    ffrag rz = {0.f, 0.f, 0.f, 0.f};
    bfrag rb0 = *(const bfrag*)&WRs[(0 * 64 + lane) * 4];
    bfrag rb1 = *(const bfrag*)&WRs[(1 * 64 + lane) * 4];
    ffrag res0 = __builtin_amdgcn_mfma_f32_16x16x32_bf16(su.v, rb0, rz, 0, 0, 0);
    ffrag res1 = __builtin_amdgcn_mfma_f32_16x16x32_bf16(su.v, rb1, rz, 0, 0, 0);

    // ---------------- epilogue: bias, ELU, mix, store ----------------
#pragma unroll
    for (int j = 0; j < 4; ++j) {
      int r = quad * 4 + j;            // C/D row = (pt, b)
      int p_e = p0 + (r >> 3);
      int b_e = r & 7;
      size_t obase = ((size_t)b_e * PP + p_e) * 32;
      float c0 = acc0[j] + bias[(size_t)p_e * 32 + lo16];
      float c1 = acc1[j] + bias[(size_t)p_e * 32 + 16 + lo16];
      float e0 = c0 > 0.f ? c0 : (__expf(c0) - 1.f);
      float e1 = c1 > 0.f ? c1 : (__expf(c1) - 1.f);
      out[obase + lo16]      = SQH * e0 + SQH * res0[j];
      out[obase + 16 + lo16] = SQH * e1 + SQH * res1[j];
    }
  }
}

extern "C" void kernel_launch(void* const* d_in, const int* in_sizes, int n_in,
                              void* d_out, int out_size, void* d_ws, size_t ws_size,
                              hipStream_t stream) {
  const float* in_pc       = (const float*)d_in[0];
  const float* weights     = (const float*)d_in[1];
  const float* bias        = (const float*)d_in[2];
  const float* w_weights   = (const float*)d_in[3];
  const float* weight_res  = (const float*)d_in[4];
  const int*   neighbor_id = (const int*)d_in[5];
  float* out = (float*)d_out;

  // 512 blocks x 4 waves x 4 pairs x 2 points = 16384 points
  hipLaunchKernelGGL(pconv_mfma, dim3(512), dim3(256), 0, stream,
                     in_pc, weights, bias, w_weights, weight_res, neighbor_id, out);
}